// Round 19
// baseline (261.631 us; speedup 1.0000x reference)
//
#include <hip/hip_runtime.h>
#include <cfloat>

typedef _Float16 half8 __attribute__((ext_vector_type(8)));
typedef float    f32x4 __attribute__((ext_vector_type(4)));
typedef unsigned int  uint;
typedef unsigned short ushort;

// Problem constants
constexpr int DIM  = 512;
constexpr int NEMB = 1024;
constexpr int HW   = 1024;
constexpr int NROW = 32 * HW;   // 32768

constexpr long long QCOUNT = (long long)32 * 512 * 32 * 32; // 16777216
constexpr long long SOFF   = QCOUNT;
constexpr long long IOFF   = SOFF + 1;

// ---------------- ws layout (bytes) ----------------
// zt: 256 mb x 16 kc tiles of (128r x 32k fp16, swizzled 64B rows) = 8KB -> 32 MB
// et: 8 nc x 16 kc tiles of (128r x 32k fp16, swizzled 64B rows)  = 8KB -> 1 MB
constexpr size_t WS_ZT    = 0;
constexpr size_t WS_ET    = 33554432;
constexpr size_t WS_ENORM = 34603008;
constexpr size_t WS_CNT   = 34607104;
constexpr size_t WS_LIST  = 34607360;                          // NROW*4
constexpr size_t WS_CANDB = WS_LIST + (size_t)NROW * 4;        // 4*NROW*8
constexpr size_t WS_CANDI = WS_CANDB + (size_t)4 * NROW * 8;   // 4*NROW*4
constexpr size_t WS_NEED  = WS_CANDI + (size_t)4 * NROW * 4;

// fp16 single-pass distance error: std ~0.018 (sigma_diff ~0.025).
// DELTA = 0.25 = 10 sigma; proven absmax=0.0 in r12-r18.
constexpr float DELTA = 0.25f;

// ---------------- helpers ----------------
__device__ __forceinline__ void gld16(const void* g, void* l) {
    __builtin_amdgcn_global_load_lds(
        (const __attribute__((address_space(1))) void*)g,
        (__attribute__((address_space(3))) void*)l, 16, 0, 0);
}
union PKH8 { half8 v; _Float16 h[8]; };

// 64B-row tile swizzle (4 x 16B granules/row): slot = g ^ ((r>>1)&3).
// Proven ~0 conflicts in r12/r13.
__device__ __forceinline__ int swz4(int r, int g) {
    return g ^ ((r >> 1) & 3);
}

// ---------------- P1 (fused): z->zt (0..2047) | e->et+enorm (2048..2303) ---
__global__ __launch_bounds__(256) void prep(const float* __restrict__ z,
                                            const float* __restrict__ e,
                                            char* __restrict__ zt,
                                            char* __restrict__ et,
                                            float* __restrict__ enorm,
                                            int* __restrict__ cnt) {
    __shared__ float ls[64][129];
    const int bx = blockIdx.x;
    const int t  = threadIdx.x;
    if (bx >= 2048) {
        // ---- eprep role (256 blocks): 128r x 32k tiles, 64B rows
        const int eb = bx - 2048;
        if (eb == 0 && t == 0) *cnt = 0;
        int gid = eb * 256 + t;                    // 0..65535
        int ke  = gid >> 6;                        // embedding row (wave-aligned)
        int kbg = gid & 63;                        // 16B-granule (= lane)
        const float* src = e + (size_t)ke * DIM + kbg * 8;
        PKH8 h;
        float s = 0.f;
        #pragma unroll
        for (int j = 0; j < 8; ++j) {
            float v = src[j];
            h.h[j] = (_Float16)v;   // RNE
            s += v * v;
        }
        int nc = ke >> 7, r = ke & 127, kc = kbg >> 2, g = kbg & 3;
        size_t byte = ((size_t)(nc * 16 + kc)) * 8192 + (size_t)r * 64
                    + ((size_t)swz4(r, g) << 4);
        *reinterpret_cast<half8*>(et + byte) = h.v;
        #pragma unroll
        for (int off = 32; off > 0; off >>= 1) s += __shfl_down(s, off, 64);
        if (kbg == 0) enorm[ke] = s;
        return;
    }
    // ---- zprep role (2048 blocks): 128r x 32k tiles (2 per 64-ch group)
    const int mb  = bx >> 3, kcc = bx & 7;     // kcc: 64-channel group
    const int b   = mb >> 3;                   // rows mb*128 -> batch
    const int hw0 = (mb & 7) * 128;
    for (int i = t; i < 64 * 128; i += 256) {
        int c = i >> 7, hw = i & 127;
        ls[c][hw] = z[((size_t)(b * DIM + kcc * 64 + c)) * HW + hw0 + hw];
    }
    __syncthreads();
    for (int j = t; j < 1024; j += 256) {
        int r = j >> 3, kbl = j & 7;
        PKH8 h;
        #pragma unroll
        for (int jj = 0; jj < 8; ++jj) h.h[jj] = (_Float16)ls[kbl * 8 + jj][r];
        int kc = kcc * 2 + (kbl >> 2), g = kbl & 3;
        size_t byte = ((size_t)(mb * 16 + kc)) * 8192 + (size_t)r * 64
                    + ((size_t)swz4(r, g) << 4);
        *reinterpret_cast<half8*>(zt + byte) = h.v;
    }
}

// ---------------- Main: TM=128, N-split x4, BK=32, depth-2, 4 blk/CU -------
// 32 steps (2 nc-chunks x 16 kc). Per step: vmcnt(2) -> barrier -> 6 ds_read
// -> lgkmcnt(0)+sched_barrier -> barrier -> stage S+2 (2 gld16) -> 8 MFMA.
#define VQ_STAGE(SS, BUF)                                                      \
  {                                                                            \
    const int kc_  = (SS) & 15;                                                \
    const int ncl_ = (SS) >> 4;                                                \
    const size_t tB_ = ((size_t)((q2 + ncl_) * 16 + kc_)) * 8192;              \
    char* dst_ = smem + (BUF) * 16384;                                         \
    gld16(zt + zbase + (size_t)kc_ * 8192 + toff, dst_ + toff);                \
    gld16(et + tB_ + toff, dst_ + 8192 + toff);                                \
  }

#define VQ_STEP(S, VMLIT, BUF)                                                 \
  {                                                                            \
    asm volatile("s_waitcnt vmcnt(" VMLIT ")" ::: "memory");                   \
    __builtin_amdgcn_s_barrier();                                              \
    const char* buf_ = smem + (BUF) * 16384;                                   \
    half8 a00 = *reinterpret_cast<const half8*>(buf_ + aoff0);                 \
    half8 a01 = *reinterpret_cast<const half8*>(buf_ + aoff1);                 \
    half8 b00 = *reinterpret_cast<const half8*>(buf_ + 8192 + boff0);          \
    half8 b01 = *reinterpret_cast<const half8*>(buf_ + 8192 + boff1);          \
    half8 b02 = *reinterpret_cast<const half8*>(buf_ + 8192 + boff2);          \
    half8 b03 = *reinterpret_cast<const half8*>(buf_ + 8192 + boff3);          \
    asm volatile("s_waitcnt lgkmcnt(0)" ::: "memory");                         \
    __builtin_amdgcn_sched_barrier(0);                                         \
    __builtin_amdgcn_s_barrier();                                              \
    if ((S) + 2 < 32) VQ_STAGE((S) + 2, BUF);                                  \
    acc[0][0] = __builtin_amdgcn_mfma_f32_16x16x32_f16(a00, b00, acc[0][0], 0, 0, 0); \
    acc[0][1] = __builtin_amdgcn_mfma_f32_16x16x32_f16(a00, b01, acc[0][1], 0, 0, 0); \
    acc[0][2] = __builtin_amdgcn_mfma_f32_16x16x32_f16(a00, b02, acc[0][2], 0, 0, 0); \
    acc[0][3] = __builtin_amdgcn_mfma_f32_16x16x32_f16(a00, b03, acc[0][3], 0, 0, 0); \
    acc[1][0] = __builtin_amdgcn_mfma_f32_16x16x32_f16(a01, b00, acc[1][0], 0, 0, 0); \
    acc[1][1] = __builtin_amdgcn_mfma_f32_16x16x32_f16(a01, b01, acc[1][1], 0, 0, 0); \
    acc[1][2] = __builtin_amdgcn_mfma_f32_16x16x32_f16(a01, b02, acc[1][2], 0, 0, 0); \
    acc[1][3] = __builtin_amdgcn_mfma_f32_16x16x32_f16(a01, b03, acc[1][3], 0, 0, 0); \
    if (((S) & 15) == 15) {                                                    \
      const int ncl_ = (S) >> 4;                                               \
      _Pragma("unroll")                                                        \
      for (int n = 0; n < 4; ++n) {                                            \
        const int lcol = ncl_ * 128 + wc * 64 + n * 16 + lr;                   \
        const float en = enorm_l[lcol];                                        \
        const int col = q * 256 + lcol;                                        \
        _Pragma("unroll")                                                      \
        for (int m = 0; m < 2; ++m) {                                          \
          _Pragma("unroll")                                                    \
          for (int qq = 0; qq < 4; ++qq) {                                     \
            float dv = en - 2.0f * acc[m][n][qq];                              \
            int sl = m * 4 + qq;                                               \
            if (dv < b1v[sl]) { b2v[sl] = b1v[sl]; b1v[sl] = dv; i1v[sl] = col; } \
            else if (dv < b2v[sl]) b2v[sl] = dv;                               \
          }                                                                    \
        }                                                                      \
      }                                                                        \
      _Pragma("unroll")                                                        \
      for (int m = 0; m < 2; ++m)                                              \
        _Pragma("unroll")                                                      \
        for (int n = 0; n < 4; ++n) acc[m][n] = (f32x4)(0.f);                  \
    }                                                                          \
  }

__global__ __launch_bounds__(512, 8) void vq_mfma(const char* __restrict__ zt,
                                                  const char* __restrict__ et,
                                                  const float* __restrict__ enorm,
                                                  float2* __restrict__ cand_b,
                                                  int* __restrict__ cand_i) {
    __shared__ __align__(16) char smem[32768];   // 2 x 16KB stage ring
    __shared__ float enorm_l[256];

    const int t = threadIdx.x;
    const int w = t >> 6, l = t & 63;
    const int lr = l & 15, hg = l >> 4;          // hg = k-granule 0..3
    const int wr = w >> 1;                        // 0..3 -> rows wr*32
    const int wc = w & 1;                         // 0..1 -> cols wc*64
    const int bid = blockIdx.x;
    const int mb = bid >> 2;                      // 0..255 (128-row group)
    const int q  = bid & 3;                       // embedding quarter
    const int q2 = q * 2;                         // first nc chunk of quarter
    const int n0 = mb * 128;

    const int swz = swz4(lr, hg) << 4;            // rows are base16+lr
    const int aoff0 = (wr * 32 + lr) * 64 + swz;
    const int aoff1 = (wr * 32 + 16 + lr) * 64 + swz;
    const int boff0 = (wc * 64 + lr) * 64 + swz;
    const int boff1 = (wc * 64 + 16 + lr) * 64 + swz;
    const int boff2 = (wc * 64 + 32 + lr) * 64 + swz;
    const int boff3 = (wc * 64 + 48 + lr) * 64 + swz;

    // stage this quarter's enorm to LDS (drains vmcnt before prologue so the
    // in-loop counted vmcnt sees only gld16s)
    if (t < 256) enorm_l[t] = enorm[q * 256 + t];
    __syncthreads();

    float b1v[8], b2v[8]; int i1v[8];
    #pragma unroll
    for (int s = 0; s < 8; ++s) { b1v[s] = FLT_MAX; b2v[s] = FLT_MAX; i1v[s] = 0; }

    const size_t zbase = (size_t)mb * 16 * 8192;
    const int toff = t * 16;

    f32x4 acc[2][4];
    #pragma unroll
    for (int m = 0; m < 2; ++m)
        #pragma unroll
        for (int n = 0; n < 4; ++n) acc[m][n] = (f32x4)(0.f);

    // prologue: stages 0..1 (4 VMEM in flight)
    VQ_STAGE(0, 0);
    VQ_STAGE(1, 1);

    for (int sp = 0; sp < 30; sp += 2) {
        VQ_STEP(sp + 0, "2", 0);
        VQ_STEP(sp + 1, "2", 1);
    }
    VQ_STEP(30, "2", 0);
    VQ_STEP(31, "0", 1);

    // ---- butterfly over the 16 col-lanes sharing each row
    #pragma unroll
    for (int s = 0; s < 8; ++s) {
        #pragma unroll
        for (int off = 1; off <= 8; off <<= 1) {
            float ob1 = __shfl_xor(b1v[s], off, 64);
            int   oi1 = __shfl_xor(i1v[s], off, 64);
            float ob2 = __shfl_xor(b2v[s], off, 64);
            if (ob1 < b1v[s] || (ob1 == b1v[s] && oi1 < i1v[s])) {
                b2v[s] = fminf(b1v[s], ob2);
                b1v[s] = ob1; i1v[s] = oi1;
            } else {
                b2v[s] = fminf(b2v[s], ob1);
            }
        }
    }
    // ---- block reduction across the 2 col-waves (overlay on dead ring)
    __syncthreads();
    float* red_b1 = reinterpret_cast<float*>(smem);          // [128][2]
    float* red_b2 = reinterpret_cast<float*>(smem + 1024);   // [128][2]
    int*   red_i1 = reinterpret_cast<int*>  (smem + 2048);   // [128][2]
    if (lr == 0) {
        #pragma unroll
        for (int s = 0; s < 8; ++s) {
            int row = wr * 32 + (s >> 2) * 16 + hg * 4 + (s & 3);
            red_b1[row * 2 + wc] = b1v[s];
            red_b2[row * 2 + wc] = b2v[s];
            red_i1[row * 2 + wc] = i1v[s];
        }
    }
    __syncthreads();
    if (t < 128) {
        float a1 = red_b1[t * 2], a2 = red_b2[t * 2]; int ai = red_i1[t * 2];
        float c1 = red_b1[t * 2 + 1], c2 = red_b2[t * 2 + 1]; int ci = red_i1[t * 2 + 1];
        float B1, B2; int I1;
        if (c1 < a1 || (c1 == a1 && ci < ai)) { B1 = c1; I1 = ci; B2 = fminf(a1, c2); }
        else                                   { B1 = a1; I1 = ai; B2 = fminf(a2, c1); }
        cand_b[(size_t)q * NROW + n0 + t] = make_float2(B1, B2);
        cand_i[(size_t)q * NROW + n0 + t] = I1;
    }
}

// ---------------- Combine: merge 4 quarters, write idx, flag, gather -------
__global__ __launch_bounds__(256) void combine(const float2* __restrict__ cand_b,
                                               const int* __restrict__ cand_i,
                                               const float* __restrict__ e,
                                               float* __restrict__ out,
                                               int* __restrict__ cnt,
                                               int* __restrict__ list) {
    __shared__ int idx_f[64];
    const int t = threadIdx.x;
    const int n0 = blockIdx.x * 64;
    if (t < 64) {
        const int row = n0 + t;
        float2 a = cand_b[row];
        float B1 = a.x, B2 = a.y;
        int   I1 = cand_i[row];
        // ascending quarters: strict < keeps lowest-index on ties
        #pragma unroll
        for (int qq = 1; qq < 4; ++qq) {
            float2 c = cand_b[(size_t)qq * NROW + row];
            int    ci = cand_i[(size_t)qq * NROW + row];
            if (c.x < B1) { B2 = fminf(B1, c.y); B1 = c.x; I1 = ci; }
            else          { B2 = fminf(B2, c.x); }
        }
        idx_f[t] = I1;
        out[IOFF + row] = (float)I1;
        if (B2 - B1 < DELTA) {
            int pos = atomicAdd(cnt, 1);
            list[pos] = row;
        }
    }
    if (blockIdx.x == 0 && t == 0) out[SOFF] = 0.0f;
    __syncthreads();

    // gather: out[b][c][hw0+row] = e[idx[row]][c]
    const int b   = n0 >> 10;
    const int hw0 = n0 & (HW - 1);
    const int row4 = (t & 15) * 4;
    const int i0 = idx_f[row4 + 0];
    const int i1 = idx_f[row4 + 1];
    const int i2 = idx_f[row4 + 2];
    const int i3 = idx_f[row4 + 3];
    #pragma unroll 4
    for (int p = 0; p < 32; ++p) {
        int c = (t >> 4) + (p << 4);
        float4 v;
        v.x = e[(size_t)i0 * DIM + c];
        v.y = e[(size_t)i1 * DIM + c];
        v.z = e[(size_t)i2 * DIM + c];
        v.w = e[(size_t)i3 * DIM + c];
        *reinterpret_cast<float4*>(&out[((size_t)(b * DIM + c)) * HW + hw0 + row4]) = v;
    }
}

// ---------------- Recheck: 4-row-batched exact fp32 re-scan ----------------
__global__ __launch_bounds__(256) void recheck(const float* __restrict__ z,
                                               const float* __restrict__ e,
                                               const float* __restrict__ enorm,
                                               const int* __restrict__ cnt,
                                               const int* __restrict__ list,
                                               float* __restrict__ out) {
    __shared__ float zrow[4][512];
    __shared__ float rb[256];
    __shared__ int   ri[256];
    __shared__ int   fidx[4];
    const int t = threadIdx.x;
    const int count = *cnt;
    const int ngrp = (count + 3) >> 2;
    for (int g = blockIdx.x; g < ngrp; g += gridDim.x) {
        const int base = g * 4;
        const int nr = min(4, count - base);
        __syncthreads();
        for (int r = 0; r < nr; ++r) {
            const int row = list[base + r];
            const int b = row >> 10, hw = row & (HW - 1);
            zrow[r][t]       = z[((size_t)(b * DIM + t))       * HW + hw];
            zrow[r][t + 256] = z[((size_t)(b * DIM + t + 256)) * HW + hw];
        }
        __syncthreads();
        float best[4]; int bi[4];
        #pragma unroll
        for (int r = 0; r < 4; ++r) { best[r] = FLT_MAX; bi[r] = 0; }
        #pragma unroll
        for (int p = 0; p < 4; ++p) {
            const int ke = t + p * 256;
            const float4* ep = reinterpret_cast<const float4*>(e + (size_t)ke * DIM);
            float d0 = 0.f, d1 = 0.f, d2 = 0.f, d3 = 0.f;
            const float4* z0 = reinterpret_cast<const float4*>(zrow[0]);
            const float4* z1 = reinterpret_cast<const float4*>(zrow[1]);
            const float4* z2 = reinterpret_cast<const float4*>(zrow[2]);
            const float4* z3 = reinterpret_cast<const float4*>(zrow[3]);
            for (int c = 0; c < 128; ++c) {
                float4 ev = ep[c];
                float4 a0 = z0[c], a1 = z1[c], a2 = z2[c], a3 = z3[c];
                d0 += ev.x*a0.x + ev.y*a0.y + ev.z*a0.z + ev.w*a0.w;
                d1 += ev.x*a1.x + ev.y*a1.y + ev.z*a1.z + ev.w*a1.w;
                d2 += ev.x*a2.x + ev.y*a2.y + ev.z*a2.z + ev.w*a2.w;
                d3 += ev.x*a3.x + ev.y*a3.y + ev.z*a3.z + ev.w*a3.w;
            }
            const float en = enorm[ke];
            float dd[4] = { en - 2.f*d0, en - 2.f*d1, en - 2.f*d2, en - 2.f*d3 };
            #pragma unroll
            for (int r = 0; r < 4; ++r)
                if (dd[r] < best[r]) { best[r] = dd[r]; bi[r] = ke; }
        }
        for (int r = 0; r < nr; ++r) {
            rb[t] = best[r]; ri[t] = bi[r];
            __syncthreads();
            #pragma unroll
            for (int s = 128; s > 0; s >>= 1) {
                if (t < s) {
                    float ov = rb[t + s]; int oi = ri[t + s];
                    if (ov < rb[t] || (ov == rb[t] && oi < ri[t])) {
                        rb[t] = ov; ri[t] = oi;
                    }
                }
                __syncthreads();
            }
            if (t == 0) {
                fidx[r] = ri[0];
                out[IOFF + list[base + r]] = (float)ri[0];
            }
            __syncthreads();
        }
        for (int r = 0; r < nr; ++r) {
            const int row = list[base + r];
            const int b = row >> 10, hw = row & (HW - 1);
            const int fbi = fidx[r];
            out[((size_t)(b * DIM + t))       * HW + hw] = e[(size_t)fbi * DIM + t];
            out[((size_t)(b * DIM + t + 256)) * HW + hw] = e[(size_t)fbi * DIM + t + 256];
        }
    }
}

// ======================= fp32 fallback path (round-2, proven) ================
constexpr int TM = 64;
constexpr int TN = 256;
constexpr int KC = 32;
constexpr int ZST = 68;
constexpr int EST = 260;

union F4 { float4 v; float f[4]; };

__global__ __launch_bounds__(256) void enorm_kernel(const float* __restrict__ e,
                                                    float* __restrict__ enorm) {
    int gid  = blockIdx.x * 256 + threadIdx.x;
    int wave = gid >> 6;
    int lane = gid & 63;
    if (wave >= NEMB) return;
    const float* row = e + (size_t)wave * DIM;
    float4 a = *reinterpret_cast<const float4*>(row + lane * 8);
    float4 b = *reinterpret_cast<const float4*>(row + lane * 8 + 4);
    float s = a.x*a.x + a.y*a.y + a.z*a.z + a.w*a.w
            + b.x*b.x + b.y*b.y + b.z*b.z + b.w*b.w;
    #pragma unroll
    for (int off = 32; off > 0; off >>= 1) s += __shfl_down(s, off, 64);
    if (lane == 0) enorm[wave] = s;
}

__global__ __launch_bounds__(256) void vq_main_kernel(const float* __restrict__ z,
                                                      const float* __restrict__ e,
                                                      const float* __restrict__ enorm,
                                                      float* __restrict__ out) {
    __shared__ float zs[KC][ZST];
    __shared__ float es[KC][EST];
    __shared__ float enorm_l[NEMB];
    __shared__ int   idx_f[TM];

    const int t   = threadIdx.x;
    const int n0  = blockIdx.x * TM;
    const int b   = n0 >> 10;
    const int hw0 = n0 & (HW - 1);
    const float* zb = z + ((size_t)b * DIM) * HW + hw0;

    #pragma unroll
    for (int i = 0; i < 4; ++i) enorm_l[t + i * 256] = enorm[t + i * 256];

    const int rg = t >> 5;
    const int cg = t & 31;

    float best[8];
    int   bidx[8];
    #pragma unroll
    for (int i = 0; i < 8; ++i) { best[i] = FLT_MAX; bidx[i] = 0; }

    const int z_r4 = (t & 15) * 4;
    const int z_c  = t >> 4;
    const int e_ke = t >> 3;
    const int e_c4 = t & 7;

    for (int nc = 0; nc < NEMB / TN; ++nc) {
        const int k0 = nc * TN;
        float acc[8][8];
        #pragma unroll
        for (int mi = 0; mi < 8; ++mi)
            #pragma unroll
            for (int nj = 0; nj < 8; ++nj) acc[mi][nj] = 0.f;

        for (int kc = 0; kc < DIM / KC; ++kc) {
            const int c0 = kc * KC;
            __syncthreads();
            #pragma unroll
            for (int p = 0; p < 2; ++p) {
                int c = z_c + p * 16;
                float4 v = *reinterpret_cast<const float4*>(zb + (size_t)(c0 + c) * HW + z_r4);
                *reinterpret_cast<float4*>(&zs[c][z_r4]) = v;
            }
            #pragma unroll
            for (int p = 0; p < 8; ++p) {
                int ke = e_ke + p * 32;
                float4 v = *reinterpret_cast<const float4*>(e + (size_t)(k0 + ke) * DIM + c0 + e_c4 * 4);
                es[e_c4 * 4 + 0][ke] = v.x;
                es[e_c4 * 4 + 1][ke] = v.y;
                es[e_c4 * 4 + 2][ke] = v.z;
                es[e_c4 * 4 + 3][ke] = v.w;
            }
            __syncthreads();
            #pragma unroll
            for (int kk = 0; kk < KC; ++kk) {
                F4 zf0, zf1, ef0, ef1;
                zf0.v = *reinterpret_cast<const float4*>(&zs[kk][rg * 8]);
                zf1.v = *reinterpret_cast<const float4*>(&zs[kk][rg * 8 + 4]);
                ef0.v = *reinterpret_cast<const float4*>(&es[kk][cg * 4]);
                ef1.v = *reinterpret_cast<const float4*>(&es[kk][128 + cg * 4]);
                #pragma unroll
                for (int mi = 0; mi < 4; ++mi) {
                    #pragma unroll
                    for (int nj = 0; nj < 4; ++nj) {
                        acc[mi][nj]         += zf0.f[mi] * ef0.f[nj];
                        acc[mi][nj + 4]     += zf0.f[mi] * ef1.f[nj];
                        acc[mi + 4][nj]     += zf1.f[mi] * ef0.f[nj];
                        acc[mi + 4][nj + 4] += zf1.f[mi] * ef1.f[nj];
                    }
                }
            }
        }
        #pragma unroll
        for (int mi = 0; mi < 8; ++mi) {
            #pragma unroll
            for (int nj = 0; nj < 8; ++nj) {
                int col = k0 + (nj < 4 ? cg * 4 + nj : 128 + cg * 4 + (nj - 4));
                float dv = enorm_l[col] - 2.0f * acc[mi][nj];
                if (dv < best[mi]) { best[mi] = dv; bidx[mi] = col; }
            }
        }
    }

    __syncthreads();
    float* best_l = reinterpret_cast<float*>(es);
    int*   idx_l  = reinterpret_cast<int*>(reinterpret_cast<char*>(es) + (size_t)TM * 33 * 4);
    #pragma unroll
    for (int mi = 0; mi < 8; ++mi) {
        int row = rg * 8 + mi;
        best_l[row * 33 + cg] = best[mi];
        idx_l[row * 33 + cg]  = bidx[mi];
    }
    __syncthreads();
    if (t < TM) {
        float bv = best_l[t * 33];
        int   bi = idx_l[t * 33];
        #pragma unroll
        for (int c = 1; c < 32; ++c) {
            float v  = best_l[t * 33 + c];
            int   ix = idx_l[t * 33 + c];
            if (v < bv || (v == bv && ix < bi)) { bv = v; bi = ix; }
        }
        idx_f[t] = bi;
        out[IOFF + n0 + t] = (float)bi;
    }
    if (blockIdx.x == 0 && t == 0) out[SOFF] = 0.0f;
    __syncthreads();

    const int row4 = (t & 15) * 4;
    const int i0 = idx_f[row4 + 0];
    const int i1 = idx_f[row4 + 1];
    const int i2 = idx_f[row4 + 2];
    const int i3 = idx_f[row4 + 3];
    #pragma unroll 4
    for (int p = 0; p < 32; ++p) {
        int c = (t >> 4) + (p << 4);
        float4 v;
        v.x = e[(size_t)i0 * DIM + c];
        v.y = e[(size_t)i1 * DIM + c];
        v.z = e[(size_t)i2 * DIM + c];
        v.w = e[(size_t)i3 * DIM + c];
        *reinterpret_cast<float4*>(&out[((size_t)(b * DIM + c)) * HW + hw0 + row4]) = v;
    }
}

// ---------------- host launcher ----------------
extern "C" void kernel_launch(void* const* d_in, const int* in_sizes, int n_in,
                              void* d_out, int out_size, void* d_ws, size_t ws_size,
                              hipStream_t stream) {
    const float* z = (const float*)d_in[0];
    const float* e = (const float*)d_in[1];
    float* out = (float*)d_out;
    char*  ws  = (char*)d_ws;

    if (ws_size >= WS_NEED) {
        char*   zt     = ws + WS_ZT;
        char*   et     = ws + WS_ET;
        float*  enorm  = (float*)(ws + WS_ENORM);
        int*    cnt    = (int*)(ws + WS_CNT);
        int*    list   = (int*)(ws + WS_LIST);
        float2* cand_b = (float2*)(ws + WS_CANDB);
        int*    cand_i = (int*)(ws + WS_CANDI);

        hipLaunchKernelGGL(prep,    dim3(2304),           dim3(256), 0, stream,
                           z, e, zt, et, enorm, cnt);
        hipLaunchKernelGGL(vq_mfma, dim3(NROW / 128 * 4), dim3(512), 0, stream,
                           zt, et, enorm, cand_b, cand_i);
        hipLaunchKernelGGL(combine, dim3(NROW / 64),      dim3(256), 0, stream,
                           cand_b, cand_i, e, out, cnt, list);
        hipLaunchKernelGGL(recheck, dim3(1024),           dim3(256), 0, stream,
                           z, e, enorm, cnt, list, out);
    } else {
        float* enorm = (float*)ws;
        hipLaunchKernelGGL(enorm_kernel,   dim3(NEMB / 4), dim3(256), 0, stream, e, enorm);
        hipLaunchKernelGGL(vq_main_kernel, dim3(NROW / TM), dim3(256), 0, stream,
                           z, e, enorm, out);
    }
}

// Round 20
// 213.737 us; speedup vs baseline: 1.2241x; 1.2241x over previous
//
#include <hip/hip_runtime.h>
#include <cfloat>

typedef _Float16 half8 __attribute__((ext_vector_type(8)));
typedef float    f32x4 __attribute__((ext_vector_type(4)));
typedef unsigned int  uint;
typedef unsigned short ushort;

// Problem constants
constexpr int DIM  = 512;
constexpr int NEMB = 1024;
constexpr int HW   = 1024;
constexpr int NROW = 32 * HW;   // 32768

constexpr long long QCOUNT = (long long)32 * 512 * 32 * 32; // 16777216
constexpr long long SOFF   = QCOUNT;
constexpr long long IOFF   = SOFF + 1;

// ---------------- ws layout (bytes) ----------------
// zt: 256 mb x 8 kc64 tiles of (128r x 64k fp16, swizzled 128B rows) = 16KB -> 32 MB
// et: 8 nc x 8 kc64 tiles of (128r x 64k fp16, swizzled 128B rows)  = 16KB -> 1 MB
constexpr size_t WS_ZT    = 0;
constexpr size_t WS_ET    = 33554432;
constexpr size_t WS_ENORM = 34603008;
constexpr size_t WS_CNT   = 34607104;
constexpr size_t WS_LIST  = 34607360;                          // NROW*4
constexpr size_t WS_CANDB = WS_LIST + (size_t)NROW * 4;        // 2*NROW*8
constexpr size_t WS_CANDI = WS_CANDB + (size_t)2 * NROW * 8;   // 2*NROW*4
constexpr size_t WS_NEED  = WS_CANDI + (size_t)2 * NROW * 4;

// fp16 single-pass distance error: std ~0.018 (sigma_diff ~0.025).
// DELTA = 0.25 = 10 sigma -> P(flip) ~ 7.6e-24 per pair, ~2e-16 overall.
constexpr float DELTA = 0.25f;

// ---------------- helpers ----------------
__device__ __forceinline__ void gld16(const void* g, void* l) {
    __builtin_amdgcn_global_load_lds(
        (const __attribute__((address_space(1))) void*)g,
        (__attribute__((address_space(3))) void*)l, 16, 0, 0);
}
union PKH8 { half8 v; _Float16 h[8]; };

// 128B-row tile swizzle (8 x 16B granules/row): slot = g ^ (r&7).
// Balanced: 64 lanes x 4 dwords = 256 touches -> exactly 8/bank (min).
__device__ __forceinline__ int swz8(int r, int g) {
    return g ^ (r & 7);
}

// ---------------- P1 (fused): z->zt (blocks 0..2047) | e->et+enorm (2048..2303)
__global__ __launch_bounds__(256) void prep(const float* __restrict__ z,
                                            const float* __restrict__ e,
                                            char* __restrict__ zt,
                                            char* __restrict__ et,
                                            float* __restrict__ enorm,
                                            int* __restrict__ cnt) {
    __shared__ float ls[64][129];
    const int bx = blockIdx.x;
    const int t  = threadIdx.x;
    if (bx >= 2048) {
        // ---- eprep role (256 blocks)
        const int eb = bx - 2048;
        if (eb == 0 && t == 0) *cnt = 0;
        int gid = eb * 256 + t;                    // 0..65535
        int ke  = gid >> 6;                        // embedding row (wave-aligned)
        int kbg = gid & 63;                        // 16B-granule (= lane)
        const float* src = e + (size_t)ke * DIM + kbg * 8;
        PKH8 h;
        float s = 0.f;
        #pragma unroll
        for (int j = 0; j < 8; ++j) {
            float v = src[j];
            h.h[j] = (_Float16)v;   // RNE
            s += v * v;
        }
        int nc = ke >> 7, r = ke & 127, kc64 = kbg >> 3, g = kbg & 7;
        size_t byte = ((size_t)(nc * 8 + kc64)) * 16384 + (size_t)r * 128
                    + ((size_t)swz8(r, g) << 4);
        *reinterpret_cast<half8*>(et + byte) = h.v;
        #pragma unroll
        for (int off = 32; off > 0; off >>= 1) s += __shfl_down(s, off, 64);
        if (kbg == 0) enorm[ke] = s;
        return;
    }
    // ---- zprep role (2048 blocks)
    const int mb  = bx >> 3, kcc = bx & 7;     // kcc = kc64 (64-channel group)
    const int b   = mb >> 3;                   // rows mb*128 -> batch
    const int hw0 = (mb & 7) * 128;
    for (int i = t; i < 64 * 128; i += 256) {
        int c = i >> 7, hw = i & 127;
        ls[c][hw] = z[((size_t)(b * DIM + kcc * 64 + c)) * HW + hw0 + hw];
    }
    __syncthreads();
    for (int j = t; j < 1024; j += 256) {
        int r = j >> 3, g = j & 7;
        PKH8 h;
        #pragma unroll
        for (int jj = 0; jj < 8; ++jj) h.h[jj] = (_Float16)ls[g * 8 + jj][r];
        size_t byte = ((size_t)(mb * 8 + kcc)) * 16384 + (size_t)r * 128
                    + ((size_t)swz8(r, g) << 4);
        *reinterpret_cast<half8*>(zt + byte) = h.v;
    }
}

// ---------------- Main: BK=64 fused, depth-2 counted-vmcnt (r14 proven) ----
#define VQ_STAGE(SS, BUF)                                                      \
  {                                                                            \
    const int kc_ = (SS) & 7;                                                  \
    const size_t tB_ = ((size_t)((half4 + ((SS) >> 3)) * 8 + kc_)) * 16384;    \
    char* dst_ = smem + (BUF) * 32768;                                         \
    gld16(zt + zbase + (size_t)kc_ * 16384 + toff,        dst_ + toff);        \
    gld16(zt + zbase + (size_t)kc_ * 16384 + 8192 + toff, dst_ + 8192 + toff); \
    gld16(et + tB_ + toff,        dst_ + 16384 + toff);                        \
    gld16(et + tB_ + 8192 + toff, dst_ + 24576 + toff);                        \
  }

#define VQ_STEP(S, VMLIT, BUF)                                                 \
  {                                                                            \
    asm volatile("s_waitcnt vmcnt(" VMLIT ")" ::: "memory");                   \
    __builtin_amdgcn_s_barrier();                                              \
    const char* buf_ = smem + (BUF) * 32768;                                   \
    half8 a00 = *reinterpret_cast<const half8*>(buf_ + aoff0);                 \
    half8 a01 = *reinterpret_cast<const half8*>(buf_ + aoff1);                 \
    half8 a10 = *reinterpret_cast<const half8*>(buf_ + (aoff0 ^ 64));          \
    half8 a11 = *reinterpret_cast<const half8*>(buf_ + (aoff1 ^ 64));          \
    half8 b00 = *reinterpret_cast<const half8*>(buf_ + 16384 + boff0);         \
    half8 b01 = *reinterpret_cast<const half8*>(buf_ + 16384 + boff1);         \
    half8 b02 = *reinterpret_cast<const half8*>(buf_ + 16384 + boff2);         \
    half8 b03 = *reinterpret_cast<const half8*>(buf_ + 16384 + boff3);         \
    half8 b10 = *reinterpret_cast<const half8*>(buf_ + 16384 + (boff0 ^ 64));  \
    half8 b11 = *reinterpret_cast<const half8*>(buf_ + 16384 + (boff1 ^ 64));  \
    half8 b12 = *reinterpret_cast<const half8*>(buf_ + 16384 + (boff2 ^ 64));  \
    half8 b13 = *reinterpret_cast<const half8*>(buf_ + 16384 + (boff3 ^ 64));  \
    asm volatile("s_waitcnt lgkmcnt(0)" ::: "memory");                         \
    __builtin_amdgcn_sched_barrier(0);                                         \
    __builtin_amdgcn_s_barrier();                                              \
    if ((S) + 2 < 32) VQ_STAGE((S) + 2, BUF);                                  \
    acc[0][0] = __builtin_amdgcn_mfma_f32_16x16x32_f16(a00, b00, acc[0][0], 0, 0, 0); \
    acc[0][1] = __builtin_amdgcn_mfma_f32_16x16x32_f16(a00, b01, acc[0][1], 0, 0, 0); \
    acc[0][2] = __builtin_amdgcn_mfma_f32_16x16x32_f16(a00, b02, acc[0][2], 0, 0, 0); \
    acc[0][3] = __builtin_amdgcn_mfma_f32_16x16x32_f16(a00, b03, acc[0][3], 0, 0, 0); \
    acc[1][0] = __builtin_amdgcn_mfma_f32_16x16x32_f16(a01, b00, acc[1][0], 0, 0, 0); \
    acc[1][1] = __builtin_amdgcn_mfma_f32_16x16x32_f16(a01, b01, acc[1][1], 0, 0, 0); \
    acc[1][2] = __builtin_amdgcn_mfma_f32_16x16x32_f16(a01, b02, acc[1][2], 0, 0, 0); \
    acc[1][3] = __builtin_amdgcn_mfma_f32_16x16x32_f16(a01, b03, acc[1][3], 0, 0, 0); \
    acc[0][0] = __builtin_amdgcn_mfma_f32_16x16x32_f16(a10, b10, acc[0][0], 0, 0, 0); \
    acc[0][1] = __builtin_amdgcn_mfma_f32_16x16x32_f16(a10, b11, acc[0][1], 0, 0, 0); \
    acc[0][2] = __builtin_amdgcn_mfma_f32_16x16x32_f16(a10, b12, acc[0][2], 0, 0, 0); \
    acc[0][3] = __builtin_amdgcn_mfma_f32_16x16x32_f16(a10, b13, acc[0][3], 0, 0, 0); \
    acc[1][0] = __builtin_amdgcn_mfma_f32_16x16x32_f16(a11, b10, acc[1][0], 0, 0, 0); \
    acc[1][1] = __builtin_amdgcn_mfma_f32_16x16x32_f16(a11, b11, acc[1][1], 0, 0, 0); \
    acc[1][2] = __builtin_amdgcn_mfma_f32_16x16x32_f16(a11, b12, acc[1][2], 0, 0, 0); \
    acc[1][3] = __builtin_amdgcn_mfma_f32_16x16x32_f16(a11, b13, acc[1][3], 0, 0, 0); \
    if (((S) & 7) == 7) {                                                      \
      const int ncl_ = ((S) >> 3) * 128;                                       \
      _Pragma("unroll")                                                        \
      for (int n = 0; n < 4; ++n) {                                            \
        const int lcol = ncl_ + wc * 64 + n * 16 + lr;                         \
        const float en = enorm_l[lcol];                                        \
        const int col = half * 512 + lcol;                                     \
        _Pragma("unroll")                                                      \
        for (int m = 0; m < 2; ++m) {                                          \
          _Pragma("unroll")                                                    \
          for (int q = 0; q < 4; ++q) {                                        \
            float dv = en - 2.0f * acc[m][n][q];                               \
            int sl = m * 4 + q;                                                \
            if (dv < b1v[sl]) { b2v[sl] = b1v[sl]; b1v[sl] = dv; i1v[sl] = col; } \
            else if (dv < b2v[sl]) b2v[sl] = dv;                               \
          }                                                                    \
        }                                                                      \
      }                                                                        \
      _Pragma("unroll")                                                        \
      for (int m = 0; m < 2; ++m)                                              \
        _Pragma("unroll")                                                      \
        for (int n = 0; n < 4; ++n) acc[m][n] = (f32x4)(0.f);                  \
    }                                                                          \
  }

__global__ __launch_bounds__(512, 4) void vq_mfma(const char* __restrict__ zt,
                                                  const char* __restrict__ et,
                                                  const float* __restrict__ enorm,
                                                  float2* __restrict__ cand_b,
                                                  int* __restrict__ cand_i) {
    __shared__ __align__(16) char smem[65536];   // 2 x 32KB stage ring
    __shared__ float enorm_l[512];

    const int t = threadIdx.x;
    const int w = t >> 6, l = t & 63;
    const int lr = l & 15, hg = l >> 4;          // hg = k-granule 0..3
    const int wr = w >> 1;                        // 0..3 -> rows wr*32
    const int wc = w & 1;                         // 0..1 -> cols wc*64
    const int bid = blockIdx.x;
    const int mb = bid >> 1;                      // 0..255 (128-row group)
    const int half = bid & 1;                     // embedding half
    const int half4 = half * 4;
    const int n0 = mb * 128;

    const int swz = swz8(lr, hg) << 4;            // slice-0 slot; slice-1 = ^64
    const int aoff0 = (wr * 32 + lr) * 128 + swz;
    const int aoff1 = (wr * 32 + 16 + lr) * 128 + swz;
    const int boff0 = (wc * 64 + lr) * 128 + swz;
    const int boff1 = (wc * 64 + 16 + lr) * 128 + swz;
    const int boff2 = (wc * 64 + 32 + lr) * 128 + swz;
    const int boff3 = (wc * 64 + 48 + lr) * 128 + swz;

    // stage this half's enorm to LDS (before prologue: drains vmcnt to 0,
    // keeps in-loop VMEM = gld16 only so the counted vmcnt stays exact)
    enorm_l[t] = enorm[half * 512 + t];
    if (t + 256 < 512) enorm_l[t + 256] = enorm[half * 512 + t + 256];
    __syncthreads();

    float b1v[8], b2v[8]; int i1v[8];
    #pragma unroll
    for (int s = 0; s < 8; ++s) { b1v[s] = FLT_MAX; b2v[s] = FLT_MAX; i1v[s] = 0; }

    const size_t zbase = (size_t)mb * 8 * 16384;
    const int toff = t * 16;

    f32x4 acc[2][4];
    #pragma unroll
    for (int m = 0; m < 2; ++m)
        #pragma unroll
        for (int n = 0; n < 4; ++n) acc[m][n] = (f32x4)(0.f);

    // prologue: stages 0..1 into buffers 0..1 (8 VMEM in flight)
    VQ_STAGE(0, 0);
    VQ_STAGE(1, 1);

    for (int sp = 0; sp < 30; sp += 2) {
        VQ_STEP(sp + 0, "4", 0);
        VQ_STEP(sp + 1, "4", 1);
    }
    VQ_STEP(30, "4", 0);
    VQ_STEP(31, "0", 1);

    // ---- butterfly over the 16 col-lanes sharing each row
    #pragma unroll
    for (int s = 0; s < 8; ++s) {
        #pragma unroll
        for (int off = 1; off <= 8; off <<= 1) {
            float ob1 = __shfl_xor(b1v[s], off, 64);
            int   oi1 = __shfl_xor(i1v[s], off, 64);
            float ob2 = __shfl_xor(b2v[s], off, 64);
            if (ob1 < b1v[s] || (ob1 == b1v[s] && oi1 < i1v[s])) {
                b2v[s] = fminf(b1v[s], ob2);
                b1v[s] = ob1; i1v[s] = oi1;
            } else {
                b2v[s] = fminf(b2v[s], ob1);
            }
        }
    }
    // ---- block reduction across the 2 col-waves (overlay on dead ring)
    __syncthreads();
    float* red_b1 = reinterpret_cast<float*>(smem);          // [128][2]
    float* red_b2 = reinterpret_cast<float*>(smem + 1024);   // [128][2]
    int*   red_i1 = reinterpret_cast<int*>  (smem + 2048);   // [128][2]
    if (lr == 0) {
        #pragma unroll
        for (int s = 0; s < 8; ++s) {
            int row = wr * 32 + (s >> 2) * 16 + hg * 4 + (s & 3);
            red_b1[row * 2 + wc] = b1v[s];
            red_b2[row * 2 + wc] = b2v[s];
            red_i1[row * 2 + wc] = i1v[s];
        }
    }
    __syncthreads();
    if (t < 128) {
        float a1 = red_b1[t * 2], a2 = red_b2[t * 2]; int ai = red_i1[t * 2];
        float c1 = red_b1[t * 2 + 1], c2 = red_b2[t * 2 + 1]; int ci = red_i1[t * 2 + 1];
        float B1, B2; int I1;
        if (c1 < a1 || (c1 == a1 && ci < ai)) { B1 = c1; I1 = ci; B2 = fminf(a1, c2); }
        else                                   { B1 = a1; I1 = ai; B2 = fminf(a2, c1); }
        cand_b[(size_t)half * NROW + n0 + t] = make_float2(B1, B2);
        cand_i[(size_t)half * NROW + n0 + t] = I1;
    }
}

// ---------------- Combine: merge halves, write idx, flag, gather -----------
__global__ __launch_bounds__(256) void combine(const float2* __restrict__ cand_b,
                                               const int* __restrict__ cand_i,
                                               const float* __restrict__ e,
                                               float* __restrict__ out,
                                               int* __restrict__ cnt,
                                               int* __restrict__ list) {
    __shared__ int idx_f[64];
    const int t = threadIdx.x;
    const int n0 = blockIdx.x * 64;
    if (t < 64) {
        const int row = n0 + t;
        float2 a = cand_b[row];
        float2 c = cand_b[NROW + row];
        int ai = cand_i[row];
        int ci = cand_i[NROW + row];
        float B1, B2; int I1;
        // half0 indices < half1 indices: strict < keeps lowest-index on ties
        if (c.x < a.x) { B1 = c.x; I1 = ci; B2 = fminf(a.x, c.y); }
        else           { B1 = a.x; I1 = ai; B2 = fminf(a.y, c.x); }
        idx_f[t] = I1;
        out[IOFF + row] = (float)I1;
        if (B2 - B1 < DELTA) {
            int pos = atomicAdd(cnt, 1);
            list[pos] = row;
        }
    }
    if (blockIdx.x == 0 && t == 0) out[SOFF] = 0.0f;
    __syncthreads();

    // gather: out[b][c][hw0+row] = e[idx[row]][c]
    const int b   = n0 >> 10;
    const int hw0 = n0 & (HW - 1);
    const int row4 = (t & 15) * 4;
    const int i0 = idx_f[row4 + 0];
    const int i1 = idx_f[row4 + 1];
    const int i2 = idx_f[row4 + 2];
    const int i3 = idx_f[row4 + 3];
    #pragma unroll 4
    for (int p = 0; p < 32; ++p) {
        int c = (t >> 4) + (p << 4);
        float4 v;
        v.x = e[(size_t)i0 * DIM + c];
        v.y = e[(size_t)i1 * DIM + c];
        v.z = e[(size_t)i2 * DIM + c];
        v.w = e[(size_t)i3 * DIM + c];
        *reinterpret_cast<float4*>(&out[((size_t)(b * DIM + c)) * HW + hw0 + row4]) = v;
    }
}

// ---------------- Recheck: 4-row-batched exact fp32 re-scan ----------------
__global__ __launch_bounds__(256) void recheck(const float* __restrict__ z,
                                               const float* __restrict__ e,
                                               const float* __restrict__ enorm,
                                               const int* __restrict__ cnt,
                                               const int* __restrict__ list,
                                               float* __restrict__ out) {
    __shared__ float zrow[4][512];
    __shared__ float rb[256];
    __shared__ int   ri[256];
    __shared__ int   fidx[4];
    const int t = threadIdx.x;
    const int count = *cnt;
    const int ngrp = (count + 3) >> 2;
    for (int g = blockIdx.x; g < ngrp; g += gridDim.x) {
        const int base = g * 4;
        const int nr = min(4, count - base);
        __syncthreads();
        for (int r = 0; r < nr; ++r) {
            const int row = list[base + r];
            const int b = row >> 10, hw = row & (HW - 1);
            zrow[r][t]       = z[((size_t)(b * DIM + t))       * HW + hw];
            zrow[r][t + 256] = z[((size_t)(b * DIM + t + 256)) * HW + hw];
        }
        __syncthreads();
        float best[4]; int bi[4];
        #pragma unroll
        for (int r = 0; r < 4; ++r) { best[r] = FLT_MAX; bi[r] = 0; }
        #pragma unroll
        for (int p = 0; p < 4; ++p) {
            const int ke = t + p * 256;
            const float4* ep = reinterpret_cast<const float4*>(e + (size_t)ke * DIM);
            float d0 = 0.f, d1 = 0.f, d2 = 0.f, d3 = 0.f;
            const float4* z0 = reinterpret_cast<const float4*>(zrow[0]);
            const float4* z1 = reinterpret_cast<const float4*>(zrow[1]);
            const float4* z2 = reinterpret_cast<const float4*>(zrow[2]);
            const float4* z3 = reinterpret_cast<const float4*>(zrow[3]);
            for (int c = 0; c < 128; ++c) {
                float4 ev = ep[c];
                float4 a0 = z0[c], a1 = z1[c], a2 = z2[c], a3 = z3[c];
                d0 += ev.x*a0.x + ev.y*a0.y + ev.z*a0.z + ev.w*a0.w;
                d1 += ev.x*a1.x + ev.y*a1.y + ev.z*a1.z + ev.w*a1.w;
                d2 += ev.x*a2.x + ev.y*a2.y + ev.z*a2.z + ev.w*a2.w;
                d3 += ev.x*a3.x + ev.y*a3.y + ev.z*a3.z + ev.w*a3.w;
            }
            const float en = enorm[ke];
            float dd[4] = { en - 2.f*d0, en - 2.f*d1, en - 2.f*d2, en - 2.f*d3 };
            #pragma unroll
            for (int r = 0; r < 4; ++r)
                if (dd[r] < best[r]) { best[r] = dd[r]; bi[r] = ke; }
        }
        for (int r = 0; r < nr; ++r) {
            rb[t] = best[r]; ri[t] = bi[r];
            __syncthreads();
            #pragma unroll
            for (int s = 128; s > 0; s >>= 1) {
                if (t < s) {
                    float ov = rb[t + s]; int oi = ri[t + s];
                    if (ov < rb[t] || (ov == rb[t] && oi < ri[t])) {
                        rb[t] = ov; ri[t] = oi;
                    }
                }
                __syncthreads();
            }
            if (t == 0) {
                fidx[r] = ri[0];
                out[IOFF + list[base + r]] = (float)ri[0];
            }
            __syncthreads();
        }
        for (int r = 0; r < nr; ++r) {
            const int row = list[base + r];
            const int b = row >> 10, hw = row & (HW - 1);
            const int fbi = fidx[r];
            out[((size_t)(b * DIM + t))       * HW + hw] = e[(size_t)fbi * DIM + t];
            out[((size_t)(b * DIM + t + 256)) * HW + hw] = e[(size_t)fbi * DIM + t + 256];
        }
    }
}

// ======================= fp32 fallback path (round-2, proven) ================
constexpr int TM = 64;
constexpr int TN = 256;
constexpr int KC = 32;
constexpr int ZST = 68;
constexpr int EST = 260;

union F4 { float4 v; float f[4]; };

__global__ __launch_bounds__(256) void enorm_kernel(const float* __restrict__ e,
                                                    float* __restrict__ enorm) {
    int gid  = blockIdx.x * 256 + threadIdx.x;
    int wave = gid >> 6;
    int lane = gid & 63;
    if (wave >= NEMB) return;
    const float* row = e + (size_t)wave * DIM;
    float4 a = *reinterpret_cast<const float4*>(row + lane * 8);
    float4 b = *reinterpret_cast<const float4*>(row + lane * 8 + 4);
    float s = a.x*a.x + a.y*a.y + a.z*a.z + a.w*a.w
            + b.x*b.x + b.y*b.y + b.z*b.z + b.w*b.w;
    #pragma unroll
    for (int off = 32; off > 0; off >>= 1) s += __shfl_down(s, off, 64);
    if (lane == 0) enorm[wave] = s;
}

__global__ __launch_bounds__(256) void vq_main_kernel(const float* __restrict__ z,
                                                      const float* __restrict__ e,
                                                      const float* __restrict__ enorm,
                                                      float* __restrict__ out) {
    __shared__ float zs[KC][ZST];
    __shared__ float es[KC][EST];
    __shared__ float enorm_l[NEMB];
    __shared__ int   idx_f[TM];

    const int t   = threadIdx.x;
    const int n0  = blockIdx.x * TM;
    const int b   = n0 >> 10;
    const int hw0 = n0 & (HW - 1);
    const float* zb = z + ((size_t)b * DIM) * HW + hw0;

    #pragma unroll
    for (int i = 0; i < 4; ++i) enorm_l[t + i * 256] = enorm[t + i * 256];

    const int rg = t >> 5;
    const int cg = t & 31;

    float best[8];
    int   bidx[8];
    #pragma unroll
    for (int i = 0; i < 8; ++i) { best[i] = FLT_MAX; bidx[i] = 0; }

    const int z_r4 = (t & 15) * 4;
    const int z_c  = t >> 4;
    const int e_ke = t >> 3;
    const int e_c4 = t & 7;

    for (int nc = 0; nc < NEMB / TN; ++nc) {
        const int k0 = nc * TN;
        float acc[8][8];
        #pragma unroll
        for (int mi = 0; mi < 8; ++mi)
            #pragma unroll
            for (int nj = 0; nj < 8; ++nj) acc[mi][nj] = 0.f;

        for (int kc = 0; kc < DIM / KC; ++kc) {
            const int c0 = kc * KC;
            __syncthreads();
            #pragma unroll
            for (int p = 0; p < 2; ++p) {
                int c = z_c + p * 16;
                float4 v = *reinterpret_cast<const float4*>(zb + (size_t)(c0 + c) * HW + z_r4);
                *reinterpret_cast<float4*>(&zs[c][z_r4]) = v;
            }
            #pragma unroll
            for (int p = 0; p < 8; ++p) {
                int ke = e_ke + p * 32;
                float4 v = *reinterpret_cast<const float4*>(e + (size_t)(k0 + ke) * DIM + c0 + e_c4 * 4);
                es[e_c4 * 4 + 0][ke] = v.x;
                es[e_c4 * 4 + 1][ke] = v.y;
                es[e_c4 * 4 + 2][ke] = v.z;
                es[e_c4 * 4 + 3][ke] = v.w;
            }
            __syncthreads();
            #pragma unroll
            for (int kk = 0; kk < KC; ++kk) {
                F4 zf0, zf1, ef0, ef1;
                zf0.v = *reinterpret_cast<const float4*>(&zs[kk][rg * 8]);
                zf1.v = *reinterpret_cast<const float4*>(&zs[kk][rg * 8 + 4]);
                ef0.v = *reinterpret_cast<const float4*>(&es[kk][cg * 4]);
                ef1.v = *reinterpret_cast<const float4*>(&es[kk][128 + cg * 4]);
                #pragma unroll
                for (int mi = 0; mi < 4; ++mi) {
                    #pragma unroll
                    for (int nj = 0; nj < 4; ++nj) {
                        acc[mi][nj]         += zf0.f[mi] * ef0.f[nj];
                        acc[mi][nj + 4]     += zf0.f[mi] * ef1.f[nj];
                        acc[mi + 4][nj]     += zf1.f[mi] * ef0.f[nj];
                        acc[mi + 4][nj + 4] += zf1.f[mi] * ef1.f[nj];
                    }
                }
            }
        }
        #pragma unroll
        for (int mi = 0; mi < 8; ++mi) {
            #pragma unroll
            for (int nj = 0; nj < 8; ++nj) {
                int col = k0 + (nj < 4 ? cg * 4 + nj : 128 + cg * 4 + (nj - 4));
                float dv = enorm_l[col] - 2.0f * acc[mi][nj];
                if (dv < best[mi]) { best[mi] = dv; bidx[mi] = col; }
            }
        }
    }

    __syncthreads();
    float* best_l = reinterpret_cast<float*>(es);
    int*   idx_l  = reinterpret_cast<int*>(reinterpret_cast<char*>(es) + (size_t)TM * 33 * 4);
    #pragma unroll
    for (int mi = 0; mi < 8; ++mi) {
        int row = rg * 8 + mi;
        best_l[row * 33 + cg] = best[mi];
        idx_l[row * 33 + cg]  = bidx[mi];
    }
    __syncthreads();
    if (t < TM) {
        float bv = best_l[t * 33];
        int   bi = idx_l[t * 33];
        #pragma unroll
        for (int c = 1; c < 32; ++c) {
            float v  = best_l[t * 33 + c];
            int   ix = idx_l[t * 33 + c];
            if (v < bv || (v == bv && ix < bi)) { bv = v; bi = ix; }
        }
        idx_f[t] = bi;
        out[IOFF + n0 + t] = (float)bi;
    }
    if (blockIdx.x == 0 && t == 0) out[SOFF] = 0.0f;
    __syncthreads();

    const int row4 = (t & 15) * 4;
    const int i0 = idx_f[row4 + 0];
    const int i1 = idx_f[row4 + 1];
    const int i2 = idx_f[row4 + 2];
    const int i3 = idx_f[row4 + 3];
    #pragma unroll 4
    for (int p = 0; p < 32; ++p) {
        int c = (t >> 4) + (p << 4);
        float4 v;
        v.x = e[(size_t)i0 * DIM + c];
        v.y = e[(size_t)i1 * DIM + c];
        v.z = e[(size_t)i2 * DIM + c];
        v.w = e[(size_t)i3 * DIM + c];
        *reinterpret_cast<float4*>(&out[((size_t)(b * DIM + c)) * HW + hw0 + row4]) = v;
    }
}

// ---------------- host launcher ----------------
extern "C" void kernel_launch(void* const* d_in, const int* in_sizes, int n_in,
                              void* d_out, int out_size, void* d_ws, size_t ws_size,
                              hipStream_t stream) {
    const float* z = (const float*)d_in[0];
    const float* e = (const float*)d_in[1];
    float* out = (float*)d_out;
    char*  ws  = (char*)d_ws;

    if (ws_size >= WS_NEED) {
        char*   zt     = ws + WS_ZT;
        char*   et     = ws + WS_ET;
        float*  enorm  = (float*)(ws + WS_ENORM);
        int*    cnt    = (int*)(ws + WS_CNT);
        int*    list   = (int*)(ws + WS_LIST);
        float2* cand_b = (float2*)(ws + WS_CANDB);
        int*    cand_i = (int*)(ws + WS_CANDI);

        hipLaunchKernelGGL(prep,    dim3(2304),           dim3(256), 0, stream,
                           z, e, zt, et, enorm, cnt);
        hipLaunchKernelGGL(vq_mfma, dim3(NROW / 128 * 2), dim3(512), 0, stream,
                           zt, et, enorm, cand_b, cand_i);
        hipLaunchKernelGGL(combine, dim3(NROW / 64),      dim3(256), 0, stream,
                           cand_b, cand_i, e, out, cnt, list);
        hipLaunchKernelGGL(recheck, dim3(1024),           dim3(256), 0, stream,
                           z, e, enorm, cnt, list, out);
    } else {
        float* enorm = (float*)ws;
        hipLaunchKernelGGL(enorm_kernel,   dim3(NEMB / 4), dim3(256), 0, stream, e, enorm);
        hipLaunchKernelGGL(vq_main_kernel, dim3(NROW / TM), dim3(256), 0, stream,
                           z, e, enorm, out);
    }
}